// Round 6
// baseline (301.792 us; speedup 1.0000x reference)
//
#include <hip/hip_runtime.h>
#include <stdint.h>

// ---------------------------------------------------------------------------
// kWTA: threshold = K-th largest of N fp32; out[i] = in[i] < thr ? 0 : in[i]
//
// Insight chain (measured across rounds):
//  - r2: in-kernel grid fusion w/ device fences = 3x slower (L2 wb/inv storms)
//  - r4: 4096-bin LDS histogram is latency-bound on same-address atomics
//        (Gaussian keys concentrate; 104us) -> histogram dropped entirely
//  - r5: fused zero-store+filter ran at 25% HBM: latency-bound, 1 load in
//        flight per wave (branch-forced vmcnt waits). Fix: let rocclr's
//        fill kernel zero the output (measured 85% peak all session) and
//        make the filter pass read-only with explicit 8x MLP.
//
// Fast path (validated at runtime, exact):
//   memset(out, 0)  -- fill-rate dense zero
//   K1: read-only filter: append (key,idx) to list A for key >= f2key(3.5)
//       (~7.8k of 33.5M for N(0,1)); 8 independent loads in flight
//   K2: fallback gather-ALL into list B -- early-exits when nA >= K
//   K3: single-block 8x4-bit radix select over full 32-bit keys -> exact
//       threshold; scatter-write winners (key >= thr) into zeroed output
// Fallback path (nA < K or overflow; never for benchmark data): list B holds
// ALL N (key,idx) pairs (512 MiB ws suffices), same select logic, exact.
// ---------------------------------------------------------------------------

// f2key(3.5f) = 0xC0600000
#define FILTER_KEY 0xC0600000u

// ctrl word offsets (ws[0..15])
//  ctrl[0] = list-A counter, ctrl[3] = threshold bits (debug), ctrl[7] = list-B counter

typedef float f32x4 __attribute__((ext_vector_type(4)));

__device__ __forceinline__ uint32_t f2key(float x) {
  uint32_t u = __float_as_uint(x);
  return (u & 0x80000000u) ? ~u : (u | 0x80000000u);  // larger key <=> larger float
}
__device__ __forceinline__ float key2f(uint32_t k) {
  uint32_t u = (k & 0x80000000u) ? (k & 0x7fffffffu) : ~k;
  return __uint_as_float(u);
}

__device__ __forceinline__ void push_cand(uint32_t kk, uint32_t idx,
                                          uint32_t* ctrl, uint32_t* keysA,
                                          uint32_t* idxsA, uint32_t capA) {
  uint32_t p = atomicAdd(&ctrl[0], 1u);
  if (p < capA) { keysA[p] = kk; idxsA[p] = idx; }
}

// K1: read-only candidate filter with 8x memory-level parallelism.
__global__ void __launch_bounds__(256) k_filter(
    const f32x4* __restrict__ in, int n4, int ntail,
    const float* __restrict__ in_s, uint32_t* __restrict__ ctrl,
    uint32_t* __restrict__ keysA, uint32_t* __restrict__ idxsA,
    uint32_t capA) {
  int gsz = gridDim.x * blockDim.x;
  int i = blockIdx.x * blockDim.x + threadIdx.x;
  // main loop: 8 independent coalesced loads in flight before any use
  for (; i + 7 * gsz < n4; i += 8 * gsz) {
    f32x4 v0 = in[i];
    f32x4 v1 = in[i + gsz];
    f32x4 v2 = in[i + 2 * gsz];
    f32x4 v3 = in[i + 3 * gsz];
    f32x4 v4 = in[i + 4 * gsz];
    f32x4 v5 = in[i + 5 * gsz];
    f32x4 v6 = in[i + 6 * gsz];
    f32x4 v7 = in[i + 7 * gsz];
#define CHECK4(vv, base)                                                       \
    {                                                                          \
      uint32_t k0 = f2key((vv).x), k1 = f2key((vv).y), k2 = f2key((vv).z),     \
               k3 = f2key((vv).w);                                             \
      if (k0 >= FILTER_KEY) push_cand(k0, (base) + 0u, ctrl, keysA, idxsA, capA); \
      if (k1 >= FILTER_KEY) push_cand(k1, (base) + 1u, ctrl, keysA, idxsA, capA); \
      if (k2 >= FILTER_KEY) push_cand(k2, (base) + 2u, ctrl, keysA, idxsA, capA); \
      if (k3 >= FILTER_KEY) push_cand(k3, (base) + 3u, ctrl, keysA, idxsA, capA); \
    }
    CHECK4(v0, 4u * (uint32_t)(i))
    CHECK4(v1, 4u * (uint32_t)(i + gsz))
    CHECK4(v2, 4u * (uint32_t)(i + 2 * gsz))
    CHECK4(v3, 4u * (uint32_t)(i + 3 * gsz))
    CHECK4(v4, 4u * (uint32_t)(i + 4 * gsz))
    CHECK4(v5, 4u * (uint32_t)(i + 5 * gsz))
    CHECK4(v6, 4u * (uint32_t)(i + 6 * gsz))
    CHECK4(v7, 4u * (uint32_t)(i + 7 * gsz))
  }
  for (; i < n4; i += gsz) {  // remainder
    f32x4 v = in[i];
    CHECK4(v, 4u * (uint32_t)i)
  }
#undef CHECK4
  if (blockIdx.x == 0 && (int)threadIdx.x < ntail) {  // scalar tail (n % 4)
    int j = n4 * 4 + threadIdx.x;
    uint32_t kk = f2key(in_s[j]);
    if (kk >= FILTER_KEY) push_cand(kk, (uint32_t)j, ctrl, keysA, idxsA, capA);
  }
}

// K2: fallback — gather ALL (key,idx) into list B. Early-exits on the fast
// path (nA >= K and list A not overflowed). Never triggers for N(0,1) data;
// exists to keep the kernel exact for arbitrary inputs.
__global__ void __launch_bounds__(256) k_gather_all(
    const float4* __restrict__ in, int n4, int ntail,
    const float* __restrict__ in_s, const int* __restrict__ kptr,
    uint32_t* __restrict__ ctrl, uint32_t* __restrict__ keysB,
    uint32_t* __restrict__ idxsB, uint32_t capA, uint32_t capB) {
  uint32_t K = (uint32_t)kptr[0];
  uint32_t nA = ctrl[0];
  if (nA >= K && nA <= capA) return;  // fast path: dispatch-cost only
  int stride = gridDim.x * blockDim.x;
  for (int i = blockIdx.x * blockDim.x + threadIdx.x; i < n4; i += stride) {
    float4 v = in[i];
    uint32_t kk[4] = {f2key(v.x), f2key(v.y), f2key(v.z), f2key(v.w)};
    uint32_t p = atomicAdd(&ctrl[7], 4u);
    for (int c = 0; c < 4; c++)
      if (p + c < capB) { keysB[p + c] = kk[c]; idxsB[p + c] = 4u * (uint32_t)i + c; }
  }
  if (blockIdx.x == 0 && (int)threadIdx.x < ntail) {
    int j = n4 * 4 + threadIdx.x;
    uint32_t p = atomicAdd(&ctrl[7], 1u);
    if (p < capB) { keysB[p] = f2key(in_s[j]); idxsB[p] = (uint32_t)j; }
  }
}

// K3: exact radix select over the full 32-bit keys (8 rounds x 4 bits) of
// the candidate list, then scatter-write winners into the zeroed output.
__global__ void __launch_bounds__(1024) k_final(
    const int* __restrict__ kptr, uint32_t* __restrict__ ctrl,
    const uint32_t* __restrict__ keysA, const uint32_t* __restrict__ idxsA,
    uint32_t capA, const uint32_t* __restrict__ keysB,
    const uint32_t* __restrict__ idxsB, uint32_t capB,
    float* __restrict__ out_s) {
  __shared__ uint32_t sh[16384];
  __shared__ uint32_t cnt[16];
  __shared__ uint32_t s_p, s_want;
  int t = threadIdx.x;
  uint32_t K = (uint32_t)kptr[0];
  uint32_t nA = ctrl[0];
  bool useA = (nA >= K && nA <= capA);
  const uint32_t* keys = useA ? keysA : keysB;
  const uint32_t* idxs = useA ? idxsA : idxsB;
  uint32_t n = useA ? nA : ctrl[7];
  if (!useA && n > capB) n = capB;
  bool useLds = (n <= 16384);
  if (useLds) for (uint32_t i = t; i < n; i += blockDim.x) sh[i] = keys[i];
  if (t == 0) { s_p = 0u; s_want = K; }
  __syncthreads();
  uint32_t p = s_p;
  for (int d = 7; d >= 0; d--) {
    if (t < 16) cnt[t] = 0;
    __syncthreads();
    int sh_hi = 4 * d + 4;  // bits above current digit (32 on first round)
    uint32_t pref = (sh_hi < 32) ? (p >> sh_hi) : 0u;
    for (uint32_t i = t; i < n; i += blockDim.x) {
      uint32_t kk = useLds ? sh[i] : keys[i];
      uint32_t hi = (sh_hi < 32) ? (kk >> sh_hi) : 0u;
      if (hi == pref) atomicAdd(&cnt[(kk >> (4 * d)) & 15u], 1u);
    }
    __syncthreads();
    if (t == 0) {
      uint32_t want = s_want, acc = 0, v = 0;
      for (int x = 15; x >= 0; x--) {
        if (acc + cnt[x] >= want) { v = (uint32_t)x; break; }
        acc += cnt[x];
      }
      s_p = p | (v << (4 * d));
      s_want = want - acc;
    }
    __syncthreads();
    p = s_p;
  }
  if (t == 0) ctrl[3] = __float_as_uint(key2f(p));
  // scatter winners: candidates at or above the exact K-th-largest key
  // (ties at the threshold value are all kept, matching where(in<thr,0,in))
  for (uint32_t i = t; i < n; i += blockDim.x) {
    uint32_t kk = useLds ? sh[i] : keys[i];
    if (kk >= p) out_s[idxs[i]] = key2f(kk);
  }
}

extern "C" void kernel_launch(void* const* d_in, const int* in_sizes, int n_in,
                              void* d_out, int out_size, void* d_ws, size_t ws_size,
                              hipStream_t stream) {
  const float* in = (const float*)d_in[0];
  const int* kptr = (const int*)d_in[1];
  float* out = (float*)d_out;
  int n = in_sizes[0];
  int n4 = n >> 2;
  int ntail = n & 3;

  uint32_t* ws = (uint32_t*)d_ws;
  uint32_t* ctrl = ws;  // 16 words
  size_t ws_words = ws_size / 4;
  size_t avail = (ws_words > 16) ? (ws_words - 16) : 0;
  uint32_t capA = (uint32_t)((avail / 4 < (1u << 20)) ? avail / 4 : (1u << 20));
  uint32_t* keysA = ws + 16;
  uint32_t* idxsA = keysA + capA;
  size_t availB = avail - 2 * (size_t)capA;
  uint32_t capB = (uint32_t)(availB / 2);  // >= N with the 512 MiB workspace
  uint32_t* keysB = idxsA + capA;
  uint32_t* idxsB = keysB + capB;

  // zero only the 64-byte control block (ws is poisoned before each launch)
  hipMemsetAsync(d_ws, 0, 16 * sizeof(uint32_t), stream);
  // dense zero of the output at fill rate (~85% HBM peak, measured);
  // winners are scatter-written by K3
  hipMemsetAsync(d_out, 0, (size_t)out_size, stream);

  k_filter<<<4096, 256, 0, stream>>>((const f32x4*)in, n4, ntail, in,
                                     ctrl, keysA, idxsA, capA);
  k_gather_all<<<2048, 256, 0, stream>>>((const float4*)in, n4, ntail, in,
                                         kptr, ctrl, keysB, idxsB, capA, capB);
  k_final<<<1, 1024, 0, stream>>>(kptr, ctrl, keysA, idxsA, capA,
                                  keysB, idxsB, capB, out);
}

// Round 7
// 279.661 us; speedup vs baseline: 1.0791x; 1.0791x over previous
//
#include <hip/hip_runtime.h>
#include <stdint.h>

// ---------------------------------------------------------------------------
// kWTA: threshold = K-th largest of N fp32; out[i] = in[i] < thr ? 0 : in[i]
//
// Insight chain (measured across rounds):
//  - r2: in-kernel grid fusion w/ device fences = 3x slower (L2 wb/inv storms)
//  - r4: 4096-bin LDS histogram is latency-bound on same-address atomics
//        (Gaussian keys concentrate; 104us) -> histogram dropped entirely
//  - r5: fused zero-store+filter at 25% HBM: latency-bound
//  - r6: DISCRIMINATOR: k_filter takes 98us even with input fully L3-resident
//        (FETCH~0 replays) -> not BW-bound. VGPR=24 proves the 8x-MLP loads
//        were sunk: atomicAdd/stores inside the loop body stop LLVM from
//        hoisting loads above them -> ~1 load in flight, latency-serialized.
//        FIX: hot loop contains NO memory ops. Candidates stash in registers
//        (4 static slots/thread), all global pushes happen after the loop.
//
// Fast path (validated at runtime, exact):
//   memset(out, 0)  -- fill-rate dense zero (rocclr fill ~85% peak, measured)
//   K1: pure-read filter over block-contiguous 128KB tiles; per-thread
//       register stash (<=4); post-loop atomic push to list A
//       (key >= f2key(3.5): ~7.8k of 33.5M for N(0,1), ~0.008 per thread)
//   K2: fallback gather-ALL into list B -- early-exits when list A valid
//   K3: single-block 8x4-bit radix select over full 32-bit keys -> exact
//       threshold; scatter-write winners (key >= thr) into zeroed output
// Fallback path (nA < K, list-A overflow, or any per-thread stash overflow;
// never for benchmark data): list B holds ALL N (key,idx) pairs, same select.
// ---------------------------------------------------------------------------

// f2key(3.5f) = 0xC0600000
#define FILTER_KEY 0xC0600000u
#define TILE 8192  // float4s per block-tile = 128 KB

// ctrl word offsets (ws[0..15])
//  ctrl[0] = list-A counter, ctrl[3] = threshold bits (debug),
//  ctrl[7] = list-B counter, ctrl[8] = stash-overflow flag

typedef float f32x4 __attribute__((ext_vector_type(4)));

__device__ __forceinline__ uint32_t f2key(float x) {
  uint32_t u = __float_as_uint(x);
  return (u & 0x80000000u) ? ~u : (u | 0x80000000u);  // larger key <=> larger float
}
__device__ __forceinline__ float key2f(uint32_t k) {
  uint32_t u = (k & 0x80000000u) ? (k & 0x7fffffffu) : ~k;
  return __uint_as_float(u);
}

// K1: pure-read candidate filter; register stash; no memory ops in hot loop.
__global__ void __launch_bounds__(256) k_filter(
    const f32x4* __restrict__ in, int n4, int ntail,
    const float* __restrict__ in_s, uint32_t* __restrict__ ctrl,
    uint32_t* __restrict__ keysA, uint32_t* __restrict__ idxsA,
    uint32_t capA) {
  int t = threadIdx.x;
  uint32_t cnt = 0;
  uint32_t rk0 = 0, rk1 = 0, rk2 = 0, rk3 = 0;
  uint32_t ri0 = 0, ri1 = 0, ri2 = 0, ri3 = 0;

  // static-slot stash: pure VALU (cndmask), no runtime-indexed array
#define STASH(kk, idx)                                                      \
  {                                                                         \
    if ((kk) >= FILTER_KEY) {                                               \
      if (cnt == 0)      { rk0 = (kk); ri0 = (idx); }                       \
      else if (cnt == 1) { rk1 = (kk); ri1 = (idx); }                       \
      else if (cnt == 2) { rk2 = (kk); ri2 = (idx); }                       \
      else if (cnt == 3) { rk3 = (kk); ri3 = (idx); }                       \
      cnt++;                                                                \
    }                                                                       \
  }
#define CHECK4(vv, base)                                                    \
  {                                                                         \
    uint32_t c0 = f2key((vv).x), c1 = f2key((vv).y), c2 = f2key((vv).z),    \
             c3 = f2key((vv).w);                                            \
    STASH(c0, (base) + 0u)                                                  \
    STASH(c1, (base) + 1u)                                                  \
    STASH(c2, (base) + 2u)                                                  \
    STASH(c3, (base) + 3u)                                                  \
  }

  int nfull = n4 / TILE;
  for (int tb = blockIdx.x; tb < nfull; tb += gridDim.x) {
    const f32x4* p = in + (size_t)tb * TILE;
    uint32_t tbase = (uint32_t)tb * (TILE * 4u);
#pragma unroll
    for (int j = 0; j < TILE / (256 * 8); ++j) {  // 4 iterations of 8x unroll
      int o = j * 2048 + t;
      // 8 independent coalesced loads; loop body has NO memory ops after
      // them, so the compiler can clause them all before the first waitcnt
      f32x4 v0 = p[o];
      f32x4 v1 = p[o + 256];
      f32x4 v2 = p[o + 512];
      f32x4 v3 = p[o + 768];
      f32x4 v4 = p[o + 1024];
      f32x4 v5 = p[o + 1280];
      f32x4 v6 = p[o + 1536];
      f32x4 v7 = p[o + 1792];
      CHECK4(v0, tbase + 4u * (uint32_t)(o))
      CHECK4(v1, tbase + 4u * (uint32_t)(o + 256))
      CHECK4(v2, tbase + 4u * (uint32_t)(o + 512))
      CHECK4(v3, tbase + 4u * (uint32_t)(o + 768))
      CHECK4(v4, tbase + 4u * (uint32_t)(o + 1024))
      CHECK4(v5, tbase + 4u * (uint32_t)(o + 1280))
      CHECK4(v6, tbase + 4u * (uint32_t)(o + 1536))
      CHECK4(v7, tbase + 4u * (uint32_t)(o + 1792))
    }
  }
  // remainder float4s (n4 % TILE), handled by block 0
  if (blockIdx.x == 0) {
    for (int i = nfull * TILE + t; i < n4; i += 256) {
      f32x4 v = in[i];
      CHECK4(v, 4u * (uint32_t)i)
    }
    if ((int)threadIdx.x < ntail) {  // scalar tail (n % 4)
      int j = n4 * 4 + threadIdx.x;
      uint32_t kk = f2key(in_s[j]);
      STASH(kk, (uint32_t)j)
    }
  }
#undef CHECK4
#undef STASH

  // cold path: push stash to global list A (one atomic per hitting thread)
  if (cnt > 4u) ctrl[8] = 1u;  // benign race; forces exact fallback
  uint32_t c = cnt > 4u ? 4u : cnt;
  if (c) {
    uint32_t p = atomicAdd(&ctrl[0], c);
    if (p < capA)     { keysA[p] = rk0;     idxsA[p] = ri0; }
    if (c > 1 && p + 1 < capA) { keysA[p + 1] = rk1; idxsA[p + 1] = ri1; }
    if (c > 2 && p + 2 < capA) { keysA[p + 2] = rk2; idxsA[p + 2] = ri2; }
    if (c > 3 && p + 3 < capA) { keysA[p + 3] = rk3; idxsA[p + 3] = ri3; }
  }
}

// K2: fallback — gather ALL (key,idx) into list B. Early-exits on the fast
// path. Never triggers for N(0,1) data; keeps the kernel exact for arbitrary
// inputs (including adversarial ones that overflow the register stash).
__global__ void __launch_bounds__(256) k_gather_all(
    const float4* __restrict__ in, int n4, int ntail,
    const float* __restrict__ in_s, const int* __restrict__ kptr,
    uint32_t* __restrict__ ctrl, uint32_t* __restrict__ keysB,
    uint32_t* __restrict__ idxsB, uint32_t capA, uint32_t capB) {
  uint32_t K = (uint32_t)kptr[0];
  uint32_t nA = ctrl[0];
  bool ok = (nA >= K) && (nA <= capA) && (ctrl[8] == 0u);
  if (ok) return;  // fast path: dispatch-cost only
  int stride = gridDim.x * blockDim.x;
  for (int i = blockIdx.x * blockDim.x + threadIdx.x; i < n4; i += stride) {
    float4 v = in[i];
    uint32_t kk[4] = {f2key(v.x), f2key(v.y), f2key(v.z), f2key(v.w)};
    uint32_t p = atomicAdd(&ctrl[7], 4u);
    for (int c = 0; c < 4; c++)
      if (p + c < capB) { keysB[p + c] = kk[c]; idxsB[p + c] = 4u * (uint32_t)i + c; }
  }
  if (blockIdx.x == 0 && (int)threadIdx.x < ntail) {
    int j = n4 * 4 + threadIdx.x;
    uint32_t p = atomicAdd(&ctrl[7], 1u);
    if (p < capB) { keysB[p] = f2key(in_s[j]); idxsB[p] = (uint32_t)j; }
  }
}

// K3: exact radix select over the full 32-bit keys (8 rounds x 4 bits) of
// the candidate list, then scatter-write winners into the zeroed output.
__global__ void __launch_bounds__(1024) k_final(
    const int* __restrict__ kptr, uint32_t* __restrict__ ctrl,
    const uint32_t* __restrict__ keysA, const uint32_t* __restrict__ idxsA,
    uint32_t capA, const uint32_t* __restrict__ keysB,
    const uint32_t* __restrict__ idxsB, uint32_t capB,
    float* __restrict__ out_s) {
  __shared__ uint32_t sh[16384];
  __shared__ uint32_t cnt[16];
  __shared__ uint32_t s_p, s_want;
  int t = threadIdx.x;
  uint32_t K = (uint32_t)kptr[0];
  uint32_t nA = ctrl[0];
  bool useA = (nA >= K) && (nA <= capA) && (ctrl[8] == 0u);
  const uint32_t* keys = useA ? keysA : keysB;
  const uint32_t* idxs = useA ? idxsA : idxsB;
  uint32_t n = useA ? nA : ctrl[7];
  if (!useA && n > capB) n = capB;
  bool useLds = (n <= 16384);
  if (useLds) for (uint32_t i = t; i < n; i += blockDim.x) sh[i] = keys[i];
  if (t == 0) { s_p = 0u; s_want = K; }
  __syncthreads();
  uint32_t p = s_p;
  for (int d = 7; d >= 0; d--) {
    if (t < 16) cnt[t] = 0;
    __syncthreads();
    int sh_hi = 4 * d + 4;  // bits above current digit (32 on first round)
    uint32_t pref = (sh_hi < 32) ? (p >> sh_hi) : 0u;
    for (uint32_t i = t; i < n; i += blockDim.x) {
      uint32_t kk = useLds ? sh[i] : keys[i];
      uint32_t hi = (sh_hi < 32) ? (kk >> sh_hi) : 0u;
      if (hi == pref) atomicAdd(&cnt[(kk >> (4 * d)) & 15u], 1u);
    }
    __syncthreads();
    if (t == 0) {
      uint32_t want = s_want, acc = 0, v = 0;
      for (int x = 15; x >= 0; x--) {
        if (acc + cnt[x] >= want) { v = (uint32_t)x; break; }
        acc += cnt[x];
      }
      s_p = p | (v << (4 * d));
      s_want = want - acc;
    }
    __syncthreads();
    p = s_p;
  }
  if (t == 0) ctrl[3] = __float_as_uint(key2f(p));
  // scatter winners: candidates at or above the exact K-th-largest key
  // (ties at the threshold value are all kept, matching where(in<thr,0,in))
  for (uint32_t i = t; i < n; i += blockDim.x) {
    uint32_t kk = useLds ? sh[i] : keys[i];
    if (kk >= p) out_s[idxs[i]] = key2f(kk);
  }
}

extern "C" void kernel_launch(void* const* d_in, const int* in_sizes, int n_in,
                              void* d_out, int out_size, void* d_ws, size_t ws_size,
                              hipStream_t stream) {
  const float* in = (const float*)d_in[0];
  const int* kptr = (const int*)d_in[1];
  float* out = (float*)d_out;
  int n = in_sizes[0];
  int n4 = n >> 2;
  int ntail = n & 3;

  uint32_t* ws = (uint32_t*)d_ws;
  uint32_t* ctrl = ws;  // 16 words
  size_t ws_words = ws_size / 4;
  size_t avail = (ws_words > 16) ? (ws_words - 16) : 0;
  uint32_t capA = (uint32_t)((avail / 4 < (1u << 20)) ? avail / 4 : (1u << 20));
  uint32_t* keysA = ws + 16;
  uint32_t* idxsA = keysA + capA;
  size_t availB = avail - 2 * (size_t)capA;
  uint32_t capB = (uint32_t)(availB / 2);  // >= N with the 512 MiB workspace
  uint32_t* keysB = idxsA + capA;
  uint32_t* idxsB = keysB + capB;

  // zero only the 64-byte control block (ws is poisoned before each launch)
  hipMemsetAsync(d_ws, 0, 16 * sizeof(uint32_t), stream);
  // dense zero of the output at fill rate (~85% HBM peak, measured);
  // winners are scatter-written by K3
  hipMemsetAsync(d_out, 0, (size_t)out_size, stream);

  k_filter<<<1024, 256, 0, stream>>>((const f32x4*)in, n4, ntail, in,
                                     ctrl, keysA, idxsA, capA);
  k_gather_all<<<2048, 256, 0, stream>>>((const float4*)in, n4, ntail, in,
                                         kptr, ctrl, keysB, idxsB, capA, capB);
  k_final<<<1, 1024, 0, stream>>>(kptr, ctrl, keysA, idxsA, capA,
                                  keysB, idxsB, capB, out);
}